// Round 11
// baseline (2211.143 us; speedup 1.0000x reference)
//
#include <hip/hip_runtime.h>
#include <hip/hip_bf16.h>

typedef __hip_bfloat16 bf16;
typedef unsigned short ushortT;
typedef __attribute__((ext_vector_type(8))) short short8;
typedef __attribute__((ext_vector_type(4))) float f32x4;

#define BB 128
#define CHAN 24
#define INNER 64
#define HW 1024
#define DD (CHAN*HW)              // 24576

constexpr size_t cBD = (size_t)BB*DD;        // 3145728 elems
constexpr size_t cYB = (size_t)BB*INNER*HW;  // 8388608 elems

// ---------------- scratch in device globals ----------------
// 24-ch activations bf16, layout [b][icv(3)][pix(1024)][8]  (c = icv*8+e)
__device__ __attribute__((aligned(16))) ushortT g_xp[cBD];
__device__ __attribute__((aligned(16))) ushortT g_X[cBD];      // current X only
__device__ __attribute__((aligned(16))) ushortT g_F[5*cBD];
__device__ __attribute__((aligned(16))) ushortT g_G[5*cBD];
__device__ __attribute__((aligned(16))) ushortT g_yb[cYB];     // [b][pix][64]
__device__ __attribute__((aligned(16))) ushortT g_tb[cBD];
__device__ __attribute__((aligned(16))) ushortT g_w1m[9*64*32]; // bf16 [s][oc64][icp32]
__device__ __attribute__((aligned(16))) ushortT g_w2m[9*24*64]; // bf16 [s][oc24][ic64]
__device__ __attribute__((aligned(16))) float g_stats2a[48];
__device__ __attribute__((aligned(16))) float g_stats2b[48];
__device__ __attribute__((aligned(16))) float g_pooled[BB*CHAN*16];
__device__ __attribute__((aligned(16))) float g_params[5120];
__device__ unsigned g_isbf16;

#define P_PCW 0
#define P_PCB 648
#define P_PBG 672
#define P_PBB 696
#define P_G1G 720
#define P_G1B 784
#define P_G2G 848
#define P_G2B 872
#define P_G3G 896
#define P_G3B 920
#define P_POG 944
#define P_POB 968
#define P_FCW 992
#define P_FCB 4832

__device__ __forceinline__ size_t aidx(int b, int icv, int pix){
  return (((size_t)b*3 + icv)*1024 + (size_t)pix)*8;
}
__device__ __forceinline__ float rdin(const void* p, int i){
  if (g_isbf16) return __bfloat162float(((const bf16*)p)[i]);
  return ((const float*)p)[i];
}
__device__ __forceinline__ float b2f(ushortT u){
  unsigned v = ((unsigned)u) << 16;
  return __builtin_bit_cast(float, v);
}
__device__ __forceinline__ ushortT f2b(float f){
  unsigned u = __builtin_bit_cast(unsigned, f);
  u += 0x7FFFu + ((u >> 16) & 1u);   // RNE
  return (ushortT)(u >> 16);
}
__device__ __forceinline__ void ld24c(const ushortT* base, int b, int pix, float* o){
  #pragma unroll
  for (int icv=0;icv<3;icv++){
    short8 v = *(const short8*)&base[aidx(b,icv,pix)];
    #pragma unroll
    for (int j=0;j<8;j++) o[icv*8+j] = b2f((ushortT)v[j]);
  }
}
__device__ __forceinline__ void st24c(ushortT* base, int b, int pix, const float* i){
  #pragma unroll
  for (int icv=0;icv<3;icv++){
    short8 v;
    #pragma unroll
    for (int j=0;j<8;j++) v[j] = (short)f2b(i[icv*8+j]);
    *(short8*)&base[aidx(b,icv,pix)] = v;
  }
}

// ---- dtype detector ----
__global__ void detect_k(const void* g1g){
  if (threadIdx.x==0 && blockIdx.x==0){
    unsigned u = *(const unsigned*)g1g;
    g_isbf16 = (u == 0x3F803F80u) ? 1u : 0u;
  }
}

// ---- convert params; zero BN sums ----
__global__ void cvt_params_k(const void* pcw, const void* pcb, const void* pbg, const void* pbb,
                             const void* g1g, const void* g1b, const void* g2g, const void* g2b,
                             const void* g3g, const void* g3b, const void* pog, const void* pob,
                             const void* fcw, const void* fcb){
  int t = threadIdx.x;
  for (int i=t;i<648;i+=256)  g_params[P_PCW+i]=rdin(pcw,i);
  for (int i=t;i<24;i+=256) { g_params[P_PCB+i]=rdin(pcb,i);
                              g_params[P_PBG+i]=rdin(pbg,i);
                              g_params[P_PBB+i]=rdin(pbb,i);
                              g_params[P_G2G+i]=rdin(g2g,i);
                              g_params[P_G2B+i]=rdin(g2b,i);
                              g_params[P_G3G+i]=rdin(g3g,i);
                              g_params[P_G3B+i]=rdin(g3b,i);
                              g_params[P_POG+i]=rdin(pog,i);
                              g_params[P_POB+i]=rdin(pob,i); }
  for (int i=t;i<64;i+=256) { g_params[P_G1G+i]=rdin(g1g,i);
                              g_params[P_G1B+i]=rdin(g1b,i); }
  for (int i=t;i<3840;i+=256) g_params[P_FCW+i]=rdin(fcw,i);
  for (int i=t;i<10;i+=256)   g_params[P_FCB+i]=rdin(fcb,i);
  for (int i=t;i<48;i+=256) { g_stats2a[i]=0.f; g_stats2b[i]=0.f; }
}

// ---- weight pack ----
__global__ void wtm_k(const void* w1, const void* w2){
  int t = blockIdx.x*256 + threadIdx.x;
  if (t < 9*64*32){
    int ic = t & 31, oc = (t>>5)&63, s9 = t>>11;
    float v = (ic<24) ? rdin(w1, (oc*24+ic)*9 + s9) : 0.f;
    g_w1m[t] = f2b(v);
  }
  int u = t - 9*64*32;
  if (u >= 0 && u < 9*24*64){
    int ic = u & 63; int rest = u >> 6; int oc = rest % 24; int s9 = rest / 24;
    g_w2m[u] = f2b(rdin(w2, (oc*64+ic)*9 + s9));
  }
}

// ---- pre conv -> g_tb chunked ----
__global__ void preconv_k(const void* __restrict__ x){
  int id = blockIdx.x*256 + threadIdx.x;
  int b = id >> 10, pix = id & 1023;
  int yy = pix >> 5, xx = pix & 31;
  float acc[24];
  #pragma unroll
  for (int oc=0;oc<24;oc++) acc[oc] = g_params[P_PCB+oc];
  for (int ic=0; ic<3; ic++)
    for (int ky=0; ky<3; ky++){
      int gy = yy+ky-1; if (gy<0||gy>=32) continue;
      for (int kx=0;kx<3;kx++){
        int gx = xx+kx-1; if (gx<0||gx>=32) continue;
        float v = rdin(x, ((b*3+ic)*32+gy)*32+gx);
        #pragma unroll
        for (int oc=0;oc<24;oc++)
          acc[oc] += v * g_params[P_PCW+(oc*3+ic)*9+ky*3+kx];
      }
    }
  st24c(g_tb, b, pix, acc);
}

// ---- BN stats ----
template<bool RELU>
__global__ void bnstat2_k(int which){
  const ushortT* src = (which==0) ? g_tb : (g_F + 4*cBD);
  float* dst = (which==0) ? g_stats2a : g_stats2b;
  __shared__ float sRed[48];
  int b = blockIdx.x >> 2, seg = blockIdx.x & 3;
  int t = threadIdx.x;
  if (t < 48) sRed[t] = 0.f;
  __syncthreads();
  int icv = t >> 6, pl = t & 63;
  float p0[8], p1[8];
  #pragma unroll
  for (int e=0;e<8;e++){ p0[e]=0.f; p1[e]=0.f; }
  for (int it=0; it<4; it++){
    int pix = seg*256 + it*64 + pl;
    short8 v = *(const short8*)&src[aidx(b,icv,pix)];
    #pragma unroll
    for (int e=0;e<8;e++){
      float f = b2f((ushortT)v[e]); if (RELU) f = fmaxf(f,0.f);
      p0[e]+=f; p1[e]+=f*f;
    }
  }
  #pragma unroll
  for (int e=0;e<8;e++){
    atomicAdd(&sRed[(icv*8+e)*2],   p0[e]);
    atomicAdd(&sRed[(icv*8+e)*2+1], p1[e]);
  }
  __syncthreads();
  if (t < 48) atomicAdd(&dst[t], sRed[t]);
}

// ---- bn apply: tb -> xp ----
__global__ void bn_apply_k(){
  int id = blockIdx.x*256+threadIdx.x;
  int b = id >> 10, pix = id & 1023;
  const float inv = 1.f/(BB*HW);
  float tv[24], ov[24];
  ld24c(g_tb, b, pix, tv);
  #pragma unroll
  for (int c=0;c<24;c++){
    float mean = g_stats2a[c*2]*inv;
    float var = fmaxf(g_stats2a[c*2+1]*inv - mean*mean, 0.f);
    float rstd = rsqrtf(var + 1e-5f);
    ov[c] = (tv[c]-mean)*rstd*g_params[P_PBG+c] + g_params[P_PBB+c];
  }
  st24c(g_xp, b, pix, ov);
}

// ---- fp64 Cholesky bordered solve, fully unrolled ----
template<int N>
__device__ __forceinline__ void chol_alpha(const float Kf[5][5], float* alpha){
  double K[N][N];
  #pragma unroll
  for (int i=0;i<N;i++)
    #pragma unroll
    for (int j=0;j<N;j++)
      K[i][j] = (double)Kf[i][j] + (i==j ? 1e-4 : 0.0);
  #pragma unroll
  for (int c=0;c<N;c++){
    double d = K[c][c];
    #pragma unroll
    for (int k2=0;k2<c;k2++) d -= K[c][k2]*K[c][k2];
    d = sqrt(fmax(d, 1e-300));
    K[c][c] = d;
    double inv = 1.0/d;
    #pragma unroll
    for (int r=c+1;r<N;r++){
      double v = K[r][c];
      #pragma unroll
      for (int k2=0;k2<c;k2++) v -= K[r][k2]*K[c][k2];
      K[r][c] = v*inv;
    }
  }
  double y[N];
  #pragma unroll
  for (int i=0;i<N;i++){
    double v = 1.0;
    #pragma unroll
    for (int j=0;j<i;j++) v -= K[i][j]*y[j];
    y[i] = v / K[i][i];
  }
  double w[N];
  #pragma unroll
  for (int i=N-1;i>=0;i--){
    double v = y[i];
    #pragma unroll
    for (int j=i+1;j<N;j++) v -= K[j][i]*w[j];
    w[i] = v / K[i][i];
  }
  double sum = 0.0;
  #pragma unroll
  for (int i=0;i<N;i++) sum += w[i];
  double invs = 1.0/sum;
  #pragma unroll
  for (int i=0;i<N;i++) alpha[i] = (float)(w[i]*invs);
}

// ================== the whole Anderson loop: 128 blocks (one/sample) x 1024 thr ==================
__launch_bounds__(1024, 1)
__global__ void anderson_k(){
  __shared__ ushortT sMem[29312];   // sA [0..10879] (21.3KB) | sW [10880..29311] (36.9KB)
  __shared__ float sGram[25], sAlpha[5], sSum1[16], sSum2[48], sSum3[16], sGrow[5], sAff[128];
  ushortT* sA = sMem;
  ushortT* sW = sMem + 10880;
  const int tid  = threadIdx.x;          // 0..1023
  const int b    = blockIdx.x;           // sample
  const int lane = tid & 63, wv = tid >> 6;   // 16 waves
  const int mLane = lane & 15, q = lane >> 4;

  #pragma unroll 1
  for (int k = 0; k < 25; k++){
    const int s  = (k < 2) ? k : (k % 5);
    const int n  = (k < 5) ? k : 5;
    const int nv = (k == 24) ? 0 : ((k+1 < 5) ? (k+1) : 5);

    // ---- phase 0: zero accumulators; solve (tid 0) ----
    __syncthreads();     // orders prev-iter sGrow->sGram copy & F/G global writes
    if (tid < 16) sSum1[tid] = 0.f;
    else if (tid < 64) sSum2[tid-16] = 0.f;
    else if (tid < 80) sSum3[tid-64] = 0.f;
    else if (tid < 85) sGrow[tid-80] = 0.f;
    if (tid == 0 && k >= 2){
      float Kf[5][5];
      for (int i=0;i<n;i++)
        for (int j=0;j<n;j++) Kf[i][j] = sGram[i*5+j];
      float al[5];
      if (n==2) chol_alpha<2>(Kf, al);
      else if (n==3) chol_alpha<3>(Kf, al);
      else if (n==4) chol_alpha<4>(Kf, al);
      else chol_alpha<5>(Kf, al);
      for (int j=0;j<n;j++) sAlpha[j] = al[j];
    }
    __syncthreads();

    // ---- phase 1: X update (slot 0 of g_X, linear over b's 24576 elems) ----
    {
      const size_t xbase = (size_t)b*DD;
      if (k == 0){
        short8 z8 = {0,0,0,0,0,0,0,0};
        for (int i=tid;i<3072;i+=1024) *(short8*)&g_X[xbase + (size_t)i*8] = z8;
      } else if (k == 1){
        for (int i=tid;i<3072;i+=1024)
          *(short8*)&g_X[xbase + (size_t)i*8] = *(const short8*)&g_F[xbase + (size_t)i*8];
      } else {
        float a[5];
        for (int j=0;j<n;j++) a[j] = sAlpha[j];
        for (int i=tid;i<3072;i+=1024){
          size_t off = xbase + (size_t)i*8;
          float acc[8];
          #pragma unroll
          for (int e=0;e<8;e++) acc[e]=0.f;
          for (int j=0;j<n;j++){
            short8 f = *(const short8*)&g_F[(size_t)j*cBD + off];
            float aj = a[j];
            #pragma unroll
            for (int e=0;e<8;e++) acc[e] += aj*b2f((ushortT)f[e]);
          }
          short8 o;
          #pragma unroll
          for (int e=0;e<8;e++) o[e] = (short)f2b(acc[e]);
          *(short8*)&g_X[off] = o;
        }
      }
    }
    __syncthreads();   // X visible

    // ---- phase 2: conv1 (4 stripes) ----
    // stage W1 once
    for (int i=tid;i<2304;i+=1024){
      int icv = i & 3, rest = i >> 2;
      int oc = rest & 63, s9 = rest >> 6;
      short8 v = *(const short8*)&g_w1m[(size_t)((s9*64 + oc)*32) + icv*8];
      *(short8*)&sW[(size_t)((s9*64+oc)*4 + (icv ^ (oc&3)))*8] = v;
    }
    for (int yt=0; yt<4; yt++){
      for (int i=tid;i<1360;i+=1024){
        int icv = i & 3, apix = i >> 2;
        int yl = apix / 34, xl = apix - yl*34;
        int gy = yt*8 - 1 + yl, gx = xl - 1;
        short8 v = {0,0,0,0,0,0,0,0};
        if (gy >= 0 && gy < 32 && gx >= 0 && gx < 32 && icv < 3)
          v = *(const short8*)&g_X[aidx(b, icv, gy*32 + gx)];
        *(short8*)&sA[(size_t)(apix*4 + (icv ^ (apix&3)))*8] = v;
      }
      __syncthreads();
      f32x4 acc1[4];
      #pragma unroll
      for (int nt=0;nt<4;nt++) acc1[nt] = (f32x4){0.f,0.f,0.f,0.f};
      for (int s9=0; s9<9; s9++){
        int ky = s9/3, kx = s9 - ky*3;
        short8 bfr[4];
        #pragma unroll
        for (int nt=0;nt<4;nt++){
          int oc = nt*16 + mLane;
          bfr[nt] = *(const short8*)&sW[(size_t)((s9*64+oc)*4 + (q ^ (oc&3)))*8];
        }
        int apix = ((wv>>1) + ky)*34 + (wv&1)*16 + mLane + kx;
        short8 afr = *(const short8*)&sA[(size_t)(apix*4 + (q ^ (apix&3)))*8];
        #pragma unroll
        for (int nt=0;nt<4;nt++)
          acc1[nt] = __builtin_amdgcn_mfma_f32_16x16x32_bf16(afr, bfr[nt], acc1[nt], 0,0,0);
      }
      // epilogue: relu -> yb + GN1 group sums
      #pragma unroll
      for (int nt=0;nt<4;nt++){
        int oc = nt*16 + mLane;
        float s0 = 0.f, s1 = 0.f;
        #pragma unroll
        for (int r=0;r<4;r++){
          int pixl = (wv>>1)*32 + (wv&1)*16 + q*4 + r;
          float v = fmaxf(acc1[nt][r], 0.f);
          s0 += v; s1 += v*v;
          g_yb[((size_t)b*1024 + yt*256 + pixl)*64 + oc] = f2b(v);
        }
        s0 += __shfl_down(s0,32); s1 += __shfl_down(s1,32);
        s0 += __shfl_down(s0,16); s1 += __shfl_down(s1,16);
        s0 += __shfl_down(s0, 4); s1 += __shfl_down(s1, 4);
        s0 += __shfl_down(s0, 2); s1 += __shfl_down(s1, 2);
        s0 += __shfl_down(s0, 1); s1 += __shfl_down(s1, 1);
        if (lane == 0){ atomicAdd(&sSum1[(nt*2+0)*2], s0); atomicAdd(&sSum1[(nt*2+0)*2+1], s1); }
        if (lane == 8){ atomicAdd(&sSum1[(nt*2+1)*2], s0); atomicAdd(&sSum1[(nt*2+1)*2+1], s1); }
      }
      __syncthreads();   // A free; after last stripe: gn1 complete
    }

    // ---- phase 3: conv2 (gn1 affine + W2) ----
    if (tid < 64){
      int c = tid, gr = c>>3;
      float S = sSum1[gr*2], Q = sSum1[gr*2+1];
      float mean = S*(1.f/8192.f);
      float var = fmaxf(Q*(1.f/8192.f) - mean*mean, 0.f);
      float rstd = rsqrtf(var + 1e-5f);
      float sc = rstd*g_params[P_G1G+c];
      sAff[c] = sc; sAff[64+c] = g_params[P_G1B+c] - mean*sc;
    }
    for (int i=tid;i<1728;i+=1024){
      int icv = i & 7, rest = i >> 3;
      int oc = rest % 24, s9 = rest / 24;
      short8 v = *(const short8*)&g_w2m[(size_t)((s9*24+oc)*64) + icv*8];
      *(short8*)&sW[(size_t)((s9*24+oc)*8 + (icv ^ (oc&7)))*8] = v;
    }
    __syncthreads();
    for (int yt=0; yt<4; yt++){
      f32x4 acc2[2];
      acc2[0] = (f32x4){0.f,0.f,0.f,0.f}; acc2[1] = (f32x4){0.f,0.f,0.f,0.f};
      const bool nt1ok = (mLane < 8);
      for (int h=0; h<2; h++){
        for (int i=tid;i<1360;i+=1024){
          int icv4 = i & 3, apix = i >> 2;
          int yl = apix / 34, xl = apix - yl*34;
          int gy = yt*8 - 1 + yl, gx = xl - 1;
          short8 v = {0,0,0,0,0,0,0,0};
          if (gy >= 0 && gy < 32 && gx >= 0 && gx < 32){
            int icv = h*4 + icv4;
            short8 raw = *(const short8*)&g_yb[((size_t)b*1024 + gy*32+gx)*64 + icv*8];
            #pragma unroll
            for (int j=0;j<8;j++){
              int c = icv*8+j;
              v[j] = (short)f2b(b2f((ushortT)raw[j])*sAff[c] + sAff[64+c]);
            }
          }
          *(short8*)&sA[(size_t)(apix*4 + (icv4 ^ (apix&3)))*8] = v;
        }
        __syncthreads();
        for (int s9=0; s9<9; s9++){
          int ky = s9/3, kx = s9 - ky*3;
          short8 bfr[2];
          { int oc = mLane;
            bfr[0] = *(const short8*)&sW[(size_t)((s9*24+oc)*8 + ((h*4+q) ^ (oc&7)))*8]; }
          if (nt1ok){
            int oc = 16 + mLane;
            bfr[1] = *(const short8*)&sW[(size_t)((s9*24+oc)*8 + ((h*4+q) ^ (oc&7)))*8];
          } else bfr[1] = (short8){0,0,0,0,0,0,0,0};
          int apix = ((wv>>1) + ky)*34 + (wv&1)*16 + mLane + kx;
          short8 afr = *(const short8*)&sA[(size_t)(apix*4 + (q ^ (apix&3)))*8];
          acc2[0] = __builtin_amdgcn_mfma_f32_16x16x32_bf16(afr, bfr[0], acc2[0], 0,0,0);
          acc2[1] = __builtin_amdgcn_mfma_f32_16x16x32_bf16(afr, bfr[1], acc2[1], 0,0,0);
        }
        __syncthreads();   // A free for next half/stripe
      }
      // epilogue: + xp -> tb global, GN2 per-channel sums
      #pragma unroll
      for (int nt=0;nt<2;nt++){
        int oc = nt*16 + mLane;
        bool ok = (oc < 24);
        int icv = oc >> 3, e = oc & 7;
        float s0=0.f, s1=0.f;
        if (ok){
          #pragma unroll
          for (int r=0;r<4;r++){
            int pix = (yt*8 + (wv>>1))*32 + (wv&1)*16 + q*4 + r;
            size_t o = aidx(b, icv, pix) + e;
            float v = acc2[nt][r] + b2f(g_xp[o]);
            g_tb[o] = f2b(v);
            s0 += v; s1 += v*v;
          }
        }
        s0 += __shfl_down(s0,32); s1 += __shfl_down(s1,32);
        s0 += __shfl_down(s0,16); s1 += __shfl_down(s1,16);
        if (lane < 16 && ok){
          atomicAdd(&sSum2[oc*2],   s0);
          atomicAdd(&sSum2[oc*2+1], s1);
        }
      }
    }
    __syncthreads();   // tb + gn2 complete

    // ---- phase 4: fuse (gn2 affine -> gn3 stats -> apply -> F,G,gram) ----
    if (tid < 24){
      int g = tid/3;
      float S = sSum2[(g*3)*2] + sSum2[(g*3+1)*2] + sSum2[(g*3+2)*2];
      float Q = sSum2[(g*3)*2+1] + sSum2[(g*3+1)*2+1] + sSum2[(g*3+2)*2+1];
      float m = S*(1.f/3072.f);
      float rs = rsqrtf(fmaxf(Q*(1.f/3072.f) - m*m, 0.f) + 1e-5f);
      float sc = rs*g_params[P_G2G+tid];
      sAff[tid] = sc; sAff[24+tid] = g_params[P_G2B+tid] - m*sc;
    }
    __syncthreads();
    {
      float tv[24], xv[24];
      ld24c(g_tb, b, tid, tv);
      ld24c(g_X, b, tid, xv);
      float p0[8], p1[8];
      #pragma unroll
      for (int g=0;g<8;g++){ p0[g]=0.f; p1[g]=0.f; }
      #pragma unroll
      for (int c=0;c<24;c++){
        int g = c/3;
        float v = fmaxf(xv[c] + tv[c]*sAff[c] + sAff[24+c], 0.f);
        p0[g] += v; p1[g] += v*v;
      }
      #pragma unroll
      for (int g=0;g<8;g++){
        for (int off=32;off>0;off>>=1){ p0[g]+=__shfl_down(p0[g],off,64); p1[g]+=__shfl_down(p1[g],off,64); }
      }
      if (lane==0){
        #pragma unroll
        for (int g=0;g<8;g++){ atomicAdd(&sSum3[g*2], p0[g]); atomicAdd(&sSum3[g*2+1], p1[g]); }
      }
      __syncthreads();
      if (tid < 24){
        int g = tid/3;
        float m3 = sSum3[g*2]*(1.f/3072.f);
        float rs3 = rsqrtf(fmaxf(sSum3[g*2+1]*(1.f/3072.f) - m3*m3, 0.f) + 1e-5f);
        float sc3 = rs3*g_params[P_G3G+tid];
        sAff[48+tid] = sc3; sAff[72+tid] = g_params[P_G3B+tid] - m3*sc3;
      }
      __syncthreads();
      float fv[24], gl[24];
      #pragma unroll
      for (int c=0;c<24;c++){
        float v = fmaxf(xv[c] + tv[c]*sAff[c] + sAff[24+c], 0.f);
        fv[c] = v*sAff[48+c] + sAff[72+c];
        gl[c] = b2f(f2b(fv[c] - xv[c]));   // bf16-rounded, matches stored G
      }
      st24c(g_F + (size_t)s*cBD, b, tid, fv);
      st24c(g_G + (size_t)s*cBD, b, tid, gl);
      if (nv > 0){
        float part[5];
        #pragma unroll
        for (int j=0;j<5;j++) part[j]=0.f;
        #pragma unroll
        for (int j=0;j<5;j++){
          if (j>=nv) continue;
          float acc=0.f;
          if (j==s){
            #pragma unroll
            for (int c=0;c<24;c++) acc += gl[c]*gl[c];
          } else {
            float gv[24];
            ld24c(g_G + (size_t)j*cBD, b, tid, gv);
            #pragma unroll
            for (int c=0;c<24;c++) acc += gl[c]*gv[c];
          }
          part[j]=acc;
        }
        #pragma unroll
        for (int j=0;j<5;j++){
          float v = part[j];
          for (int off=32;off>0;off>>=1) v += __shfl_down(v,off,64);
          if (lane==0 && j<nv) atomicAdd(&sGrow[j], v);
        }
      }
    }
    __syncthreads();   // gram partials done
    if (tid == 0 && nv > 0){
      for (int j=0;j<nv;j++){ sGram[s*5+j] = sGrow[j]; sGram[j*5+s] = sGrow[j]; }
    }
    // loop-top __syncthreads orders this copy before zeroing
  }
}

// ---- post: bn(relu(F[4])) + 8x8 avgpool ----
__global__ void post_pool_k(){
  int i = blockIdx.x*256+threadIdx.x; if (i >= BB*CHAN*16) return;
  const ushortT* z = g_F + 4*cBD;
  int pw = i&3, ph=(i>>2)&3, c=(i>>4)%CHAN, bi=i/(CHAN*16);
  int icv = c>>3, e = c&7;
  float inv = 1.f/(BB*HW);
  float mean = g_stats2b[c*2]*inv;
  float var = fmaxf(g_stats2b[c*2+1]*inv - mean*mean, 0.f);
  float rstd = rsqrtf(var + 1e-5f);
  float gg=g_params[P_POG+c], bv=g_params[P_POB+c];
  float s=0.f;
  for (int dy=0;dy<8;dy++)
    for (int dx=0;dx<8;dx++){
      int pix = (ph*8+dy)*32 + pw*8+dx;
      float v = fmaxf(b2f(z[aidx(bi,icv,pix) + e]), 0.f);
      s += (v-mean)*rstd*gg + bv;
    }
  g_pooled[i] = s*(1.f/64.f);
}

__global__ void fc_k(void* __restrict__ out){
  int i = blockIdx.x*256+threadIdx.x; if (i>=BB*10) return;
  int j=i%10, bi=i/10;
  float s = g_params[P_FCB+j];
  for (int k=0;k<384;k++) s += g_pooled[bi*384+k]*g_params[P_FCW+j*384+k];
  if (g_isbf16) ((bf16*)out)[i] = __float2bfloat16(s);
  else ((float*)out)[i] = s;
}

extern "C" void kernel_launch(void* const* d_in, const int* in_sizes, int n_in,
                              void* d_out, int out_size, void* d_ws, size_t ws_size,
                              hipStream_t stream){
  const void* x   = d_in[0];
  const void* pcw = d_in[1];
  const void* pcb = d_in[2];
  const void* pbg = d_in[3];
  const void* pbb = d_in[4];
  const void* w1  = d_in[5];
  const void* g1g = d_in[6];
  const void* g1b = d_in[7];
  const void* w2  = d_in[8];
  const void* g2g = d_in[9];
  const void* g2b = d_in[10];
  const void* g3g = d_in[11];
  const void* g3b = d_in[12];
  const void* pog = d_in[13];
  const void* pob = d_in[14];
  const void* fcw = d_in[15];
  const void* fcb = d_in[16];
  (void)d_ws; (void)ws_size;

  const int gPix = (int)(BB*HW/256); // 512

  detect_k<<<1,64,0,stream>>>(g1g);
  cvt_params_k<<<1,256,0,stream>>>(pcw,pcb,pbg,pbb,g1g,g1b,g2g,g2b,g3g,g3b,pog,pob,fcw,fcb);
  wtm_k<<<126,256,0,stream>>>(w1, w2);

  // pre stage
  preconv_k<<<gPix,256,0,stream>>>(x);
  bnstat2_k<false><<<512,192,0,stream>>>(0);
  bn_apply_k<<<gPix,256,0,stream>>>();

  // full Anderson loop: one kernel, one block per sample
  anderson_k<<<128,1024,0,stream>>>();

  // post
  bnstat2_k<true><<<512,192,0,stream>>>(1);
  post_pool_k<<<(BB*CHAN*16+255)/256,256,0,stream>>>();
  fc_k<<<(BB*10+255)/256,256,0,stream>>>(d_out);
}

// Round 13
// 1602.335 us; speedup vs baseline: 1.3800x; 1.3800x over previous
//
#include <hip/hip_runtime.h>
#include <hip/hip_bf16.h>

typedef __hip_bfloat16 bf16;
typedef unsigned short ushortT;
typedef __attribute__((ext_vector_type(8))) short short8;
typedef __attribute__((ext_vector_type(4))) float f32x4;

#define BB 128
#define CHAN 24
#define INNER 64
#define HW 1024
#define DD (CHAN*HW)              // 24576

constexpr size_t cBD = (size_t)BB*DD;        // 3145728 elems
constexpr size_t cYB = (size_t)BB*INNER*HW;  // 8388608 elems

// ---------------- scratch in device globals ----------------
// 24-ch activations bf16, layout [b][icv(3)][pix(1024)][8]  (c = icv*8+e)
__device__ __attribute__((aligned(16))) ushortT g_xp[cBD];
__device__ __attribute__((aligned(16))) ushortT g_X[5*cBD];
__device__ __attribute__((aligned(16))) ushortT g_F[5*cBD];
__device__ __attribute__((aligned(16))) ushortT g_G[5*cBD];
__device__ __attribute__((aligned(16))) ushortT g_yb[cYB];     // [b][pix][64]
__device__ __attribute__((aligned(16))) ushortT g_tb[cBD];
__device__ __attribute__((aligned(16))) ushortT g_w1m[9*64*32];
__device__ __attribute__((aligned(16))) ushortT g_w2m[9*24*64];
__device__ __attribute__((aligned(16))) float g_stats2a[48];
__device__ __attribute__((aligned(16))) float g_stats2b[48];
__device__ __attribute__((aligned(16))) float g_gn1sum[BB*8*2];
__device__ __attribute__((aligned(16))) float g_gn2sum[BB*24*2];
__device__ __attribute__((aligned(16))) float g_gramp[BB*4*5*5];  // per-(b,seg) gram row partials, write-once
__device__ __attribute__((aligned(16))) float g_gram[BB*25];      // persistent; refreshed in xns_k
__device__ __attribute__((aligned(16))) float g_pooled[BB*CHAN*16];
__device__ __attribute__((aligned(16))) float g_params[5120];
__device__ unsigned g_isbf16;

#define P_PCW 0
#define P_PCB 648
#define P_PBG 672
#define P_PBB 696
#define P_G1G 720
#define P_G1B 784
#define P_G2G 848
#define P_G2B 872
#define P_G3G 896
#define P_G3B 920
#define P_POG 944
#define P_POB 968
#define P_FCW 992
#define P_FCB 4832

__device__ __forceinline__ size_t aidx(int b, int icv, int pix){
  return (((size_t)b*3 + icv)*1024 + (size_t)pix)*8;
}
__device__ __forceinline__ float rdin(const void* p, int i){
  if (g_isbf16) return __bfloat162float(((const bf16*)p)[i]);
  return ((const float*)p)[i];
}
__device__ __forceinline__ float b2f(ushortT u){
  unsigned v = ((unsigned)u) << 16;
  return __builtin_bit_cast(float, v);
}
__device__ __forceinline__ ushortT f2b(float f){
  unsigned u = __builtin_bit_cast(unsigned, f);
  u += 0x7FFFu + ((u >> 16) & 1u);   // RNE
  return (ushortT)(u >> 16);
}
__device__ __forceinline__ void ld24c(const ushortT* base, int b, int pix, float* o){
  #pragma unroll
  for (int icv=0;icv<3;icv++){
    short8 v = *(const short8*)&base[aidx(b,icv,pix)];
    #pragma unroll
    for (int j=0;j<8;j++) o[icv*8+j] = b2f((ushortT)v[j]);
  }
}
__device__ __forceinline__ void st24c(ushortT* base, int b, int pix, const float* i){
  #pragma unroll
  for (int icv=0;icv<3;icv++){
    short8 v;
    #pragma unroll
    for (int j=0;j<8;j++) v[j] = (short)f2b(i[icv*8+j]);
    *(short8*)&base[aidx(b,icv,pix)] = v;
  }
}

// ---- dtype detector ----
__global__ void detect_k(const void* g1g){
  if (threadIdx.x==0 && blockIdx.x==0){
    unsigned u = *(const unsigned*)g1g;
    g_isbf16 = (u == 0x3F803F80u) ? 1u : 0u;
  }
}

// ---- convert params; zero BN sums ----
__global__ void cvt_params_k(const void* pcw, const void* pcb, const void* pbg, const void* pbb,
                             const void* g1g, const void* g1b, const void* g2g, const void* g2b,
                             const void* g3g, const void* g3b, const void* pog, const void* pob,
                             const void* fcw, const void* fcb){
  int t = threadIdx.x;
  for (int i=t;i<648;i+=256)  g_params[P_PCW+i]=rdin(pcw,i);
  for (int i=t;i<24;i+=256) { g_params[P_PCB+i]=rdin(pcb,i);
                              g_params[P_PBG+i]=rdin(pbg,i);
                              g_params[P_PBB+i]=rdin(pbb,i);
                              g_params[P_G2G+i]=rdin(g2g,i);
                              g_params[P_G2B+i]=rdin(g2b,i);
                              g_params[P_G3G+i]=rdin(g3g,i);
                              g_params[P_G3B+i]=rdin(g3b,i);
                              g_params[P_POG+i]=rdin(pog,i);
                              g_params[P_POB+i]=rdin(pob,i); }
  for (int i=t;i<64;i+=256) { g_params[P_G1G+i]=rdin(g1g,i);
                              g_params[P_G1B+i]=rdin(g1b,i); }
  for (int i=t;i<3840;i+=256) g_params[P_FCW+i]=rdin(fcw,i);
  for (int i=t;i<10;i+=256)   g_params[P_FCB+i]=rdin(fcb,i);
  for (int i=t;i<48;i+=256) { g_stats2a[i]=0.f; g_stats2b[i]=0.f; }
}

// ---- weight pack ----
__global__ void wtm_k(const void* w1, const void* w2){
  int t = blockIdx.x*256 + threadIdx.x;
  if (t < 9*64*32){
    int ic = t & 31, oc = (t>>5)&63, s9 = t>>11;
    float v = (ic<24) ? rdin(w1, (oc*24+ic)*9 + s9) : 0.f;
    g_w1m[t] = f2b(v);
  }
  int u = t - 9*64*32;
  if (u >= 0 && u < 9*24*64){
    int ic = u & 63; int rest = u >> 6; int oc = rest % 24; int s9 = rest / 24;
    g_w2m[u] = f2b(rdin(w2, (oc*64+ic)*9 + s9));
  }
}

// grid 1536: zero X0 (short8), + gn1sum zero
__global__ void zeroX0_k(){
  size_t i = ((size_t)blockIdx.x*256 + threadIdx.x)*8;
  short8 z = {0,0,0,0,0,0,0,0};
  *(short8*)&g_X[i] = z;
  if (blockIdx.x < 8) g_gn1sum[blockIdx.x*256 + threadIdx.x] = 0.f;
}
__global__ void copyF0toX1_k(){
  size_t i = ((size_t)blockIdx.x*256 + threadIdx.x)*8;
  *(short8*)&g_X[cBD + i] = *(const short8*)&g_F[i];
  if (blockIdx.x < 8) g_gn1sum[blockIdx.x*256 + threadIdx.x] = 0.f;
}

// ---- pre conv -> g_tb chunked ----
__global__ void preconv_k(const void* __restrict__ x){
  int id = blockIdx.x*256 + threadIdx.x;
  int b = id >> 10, pix = id & 1023;
  int yy = pix >> 5, xx = pix & 31;
  float acc[24];
  #pragma unroll
  for (int oc=0;oc<24;oc++) acc[oc] = g_params[P_PCB+oc];
  for (int ic=0; ic<3; ic++)
    for (int ky=0; ky<3; ky++){
      int gy = yy+ky-1; if (gy<0||gy>=32) continue;
      for (int kx=0;kx<3;kx++){
        int gx = xx+kx-1; if (gx<0||gx>=32) continue;
        float v = rdin(x, ((b*3+ic)*32+gy)*32+gx);
        #pragma unroll
        for (int oc=0;oc<24;oc++)
          acc[oc] += v * g_params[P_PCW+(oc*3+ic)*9+ky*3+kx];
      }
    }
  st24c(g_tb, b, pix, acc);
}

// ---- BN stats ----
template<bool RELU>
__global__ void bnstat2_k(int which){
  const ushortT* src = (which==0) ? g_tb : (g_F + 4*cBD);
  float* dst = (which==0) ? g_stats2a : g_stats2b;
  __shared__ float sRed[48];
  int b = blockIdx.x >> 2, seg = blockIdx.x & 3;
  int t = threadIdx.x;
  if (t < 48) sRed[t] = 0.f;
  __syncthreads();
  int icv = t >> 6, pl = t & 63;
  float p0[8], p1[8];
  #pragma unroll
  for (int e=0;e<8;e++){ p0[e]=0.f; p1[e]=0.f; }
  for (int it=0; it<4; it++){
    int pix = seg*256 + it*64 + pl;
    short8 v = *(const short8*)&src[aidx(b,icv,pix)];
    #pragma unroll
    for (int e=0;e<8;e++){
      float f = b2f((ushortT)v[e]); if (RELU) f = fmaxf(f,0.f);
      p0[e]+=f; p1[e]+=f*f;
    }
  }
  #pragma unroll
  for (int e=0;e<8;e++){
    atomicAdd(&sRed[(icv*8+e)*2],   p0[e]);
    atomicAdd(&sRed[(icv*8+e)*2+1], p1[e]);
  }
  __syncthreads();
  if (t < 48) atomicAdd(&dst[t], sRed[t]);
}

// ---- bn apply: tb -> xp ----
__global__ void bn_apply_k(){
  int id = blockIdx.x*256+threadIdx.x;
  int b = id >> 10, pix = id & 1023;
  const float inv = 1.f/(BB*HW);
  float tv[24], ov[24];
  ld24c(g_tb, b, pix, tv);
  #pragma unroll
  for (int c=0;c<24;c++){
    float mean = g_stats2a[c*2]*inv;
    float var = fmaxf(g_stats2a[c*2+1]*inv - mean*mean, 0.f);
    float rstd = rsqrtf(var + 1e-5f);
    ov[c] = (tv[c]-mean)*rstd*g_params[P_PBG+c] + g_params[P_PBB+c];
  }
  st24c(g_xp, b, pix, ov);
}

// ============ conv1 MFMA: X[s] -> yb=relu(conv) bf16 + GN1 sums ============
__launch_bounds__(256, 2)
__global__ void conv1_k(int s){
  __shared__ ushortT sMem[29312];   // sA 10880 | sW 18432 ; reused as sOut(16384)
  ushortT* sA = sMem;
  ushortT* sW = sMem + 10880;
  const int tid = threadIdx.x;
  const int lane = tid & 63, wv = tid >> 6;
  const int mLane = lane & 15, q = lane >> 4;
  const int b = blockIdx.x >> 2, yt = blockIdx.x & 3;
  const ushortT* __restrict__ Xs = g_X + (size_t)s*cBD;
  if (blockIdx.x < 24) g_gn2sum[blockIdx.x*256 + tid] = 0.f;   // zero for conv2's atomics
  // stage A: 10x34 halo, chunks icv 0..3 (icv<3 real), swizzle icv^(apix&3)
  for (int i = tid; i < 1360; i += 256){
    int icv = i & 3, apix = i >> 2;
    int yl = apix / 34, xl = apix - yl*34;
    int gy = yt*8 - 1 + yl, gx = xl - 1;
    short8 v = {0,0,0,0,0,0,0,0};
    if (gy >= 0 && gy < 32 && gx >= 0 && gx < 32 && icv < 3)
      v = *(const short8*)&Xs[aidx(b, icv, gy*32 + gx)];
    *(short8*)&sA[(size_t)(apix*4 + (icv ^ (apix&3)))*8] = v;
  }
  // stage W
  for (int i = tid; i < 2304; i += 256){
    int icv = i & 3, rest = i >> 2;
    int oc = rest & 63, s9 = rest >> 6;
    short8 v = *(const short8*)&g_w1m[(size_t)((s9*64 + oc)*32) + icv*8];
    *(short8*)&sW[(size_t)((s9*64+oc)*4 + (icv ^ (oc&3)))*8] = v;
  }
  __syncthreads();
  f32x4 acc[4][4];
  #pragma unroll
  for (int mt=0;mt<4;mt++)
    #pragma unroll
    for (int nt=0;nt<4;nt++) acc[mt][nt] = (f32x4){0.f,0.f,0.f,0.f};
  for (int s9=0; s9<9; s9++){
    int ky = s9/3, kx = s9 - ky*3;
    short8 bfr[4];
    #pragma unroll
    for (int nt=0;nt<4;nt++){
      int oc = nt*16 + mLane;
      bfr[nt] = *(const short8*)&sW[(size_t)((s9*64+oc)*4 + (q ^ (oc&3)))*8];
    }
    #pragma unroll
    for (int mt=0;mt<4;mt++){
      int g = wv*4+mt;
      int apix = ((g>>1) + ky)*34 + (g&1)*16 + mLane + kx;
      short8 afr = *(const short8*)&sA[(size_t)(apix*4 + (q ^ (apix&3)))*8];
      #pragma unroll
      for (int nt=0;nt<4;nt++)
        acc[mt][nt] = __builtin_amdgcn_mfma_f32_16x16x32_bf16(afr, bfr[nt], acc[mt][nt], 0,0,0);
    }
  }
  __syncthreads();
  ushortT* sOut = sMem;
  #pragma unroll
  for (int mt=0;mt<4;mt++){
    int g = wv*4+mt;
    #pragma unroll
    for (int nt=0;nt<4;nt++){
      int oc = nt*16 + mLane;
      #pragma unroll
      for (int r=0;r<4;r++){
        int pix = (g>>1)*32 + (g&1)*16 + q*4 + r;
        sOut[pix*64 + oc] = f2b(fmaxf(acc[mt][nt][r], 0.f));
      }
    }
  }
  __syncthreads();
  float s0=0.f, s1=0.f;
  size_t gbase = ((size_t)b*1024 + yt*256)*64;
  for (int c = tid; c < 2048; c += 256){
    short8 v = *(const short8*)&sOut[c*8];
    *(short8*)&g_yb[gbase + (size_t)c*8] = v;
    #pragma unroll
    for (int j=0;j<8;j++){ float f = b2f((ushortT)v[j]); s0 += f; s1 += f*f; }
  }
  s0 += __shfl_down(s0,32); s1 += __shfl_down(s1,32);
  s0 += __shfl_down(s0,16); s1 += __shfl_down(s1,16);
  s0 += __shfl_down(s0, 8); s1 += __shfl_down(s1, 8);
  if (lane < 8){
    atomicAdd(&g_gn1sum[(b*8+lane)*2],   s0);
    atomicAdd(&g_gn1sum[(b*8+lane)*2+1], s1);
  }
}

// ====== conv2 MFMA: gn1(yb) -> tb = conv + xp + GN2 sums ======
__launch_bounds__(256, 2)
__global__ void conv2_k(){
  __shared__ ushortT sMem[35584];   // sA 21760 | sW 13824
  __shared__ float sAff[128];
  ushortT* sA = sMem;
  ushortT* sW = sMem + 21760;
  const int tid = threadIdx.x;
  const int lane = tid & 63, wv = tid >> 6;
  const int mLane = lane & 15, q = lane >> 4;
  const int b = blockIdx.x >> 2, yt = blockIdx.x & 3;
  if (tid < 64){
    int c = tid, gr = c>>3;
    float S = g_gn1sum[(b*8+gr)*2], Q = g_gn1sum[(b*8+gr)*2+1];
    float mean = S*(1.f/8192.f);
    float var = fmaxf(Q*(1.f/8192.f) - mean*mean, 0.f);
    float rstd = rsqrtf(var + 1e-5f);
    float sc = rstd*g_params[P_G1G+c];
    sAff[c] = sc; sAff[64+c] = g_params[P_G1B+c] - mean*sc;
  }
  __syncthreads();
  for (int i = tid; i < 2720; i += 256){
    int icv = i & 7, apix = i >> 3;
    int yl = apix / 34, xl = apix - yl*34;
    int gy = yt*8 - 1 + yl, gx = xl - 1;
    short8 v = {0,0,0,0,0,0,0,0};
    if (gy >= 0 && gy < 32 && gx >= 0 && gx < 32){
      short8 raw = *(const short8*)&g_yb[((size_t)b*1024 + gy*32+gx)*64 + icv*8];
      #pragma unroll
      for (int j=0;j<8;j++){
        int c = icv*8+j;
        v[j] = (short)f2b(b2f((ushortT)raw[j])*sAff[c] + sAff[64+c]);
      }
    }
    *(short8*)&sA[(size_t)(apix*8 + (icv ^ (apix&7)))*8] = v;
  }
  for (int i = tid; i < 1728; i += 256){
    int icv = i & 7, rest = i >> 3;
    int oc = rest % 24, s9 = rest / 24;
    short8 v = *(const short8*)&g_w2m[(size_t)((s9*24+oc)*64) + icv*8];
    *(short8*)&sW[(size_t)((s9*24+oc)*8 + (icv ^ (oc&7)))*8] = v;
  }
  __syncthreads();
  f32x4 acc[4][2];
  #pragma unroll
  for (int mt=0;mt<4;mt++){ acc[mt][0]=(f32x4){0.f,0.f,0.f,0.f}; acc[mt][1]=(f32x4){0.f,0.f,0.f,0.f}; }
  const bool nt1ok = (mLane < 8);
  for (int s9=0; s9<9; s9++){
    int ky = s9/3, kx = s9 - ky*3;
    #pragma unroll
    for (int ks=0; ks<2; ks++){
      int ib = ks*4;
      short8 bfr[2];
      { int oc = mLane;
        bfr[0] = *(const short8*)&sW[(size_t)((s9*24+oc)*8 + ((ib+q) ^ (oc&7)))*8]; }
      if (nt1ok){
        int oc = 16 + mLane;
        bfr[1] = *(const short8*)&sW[(size_t)((s9*24+oc)*8 + ((ib+q) ^ (oc&7)))*8];
      } else bfr[1] = (short8){0,0,0,0,0,0,0,0};
      #pragma unroll
      for (int mt=0;mt<4;mt++){
        int g = wv*4+mt;
        int apix = ((g>>1) + ky)*34 + (g&1)*16 + mLane + kx;
        short8 afr = *(const short8*)&sA[(size_t)(apix*8 + ((ib+q) ^ (apix&7)))*8];
        acc[mt][0] = __builtin_amdgcn_mfma_f32_16x16x32_bf16(afr, bfr[0], acc[mt][0], 0,0,0);
        acc[mt][1] = __builtin_amdgcn_mfma_f32_16x16x32_bf16(afr, bfr[1], acc[mt][1], 0,0,0);
      }
    }
  }
  #pragma unroll
  for (int nt=0;nt<2;nt++){
    int oc = nt*16 + mLane;
    bool ok = (oc < 24);
    int icv = oc >> 3, e = oc & 7;
    float s0=0.f, s1=0.f;
    if (ok){
      #pragma unroll
      for (int mt=0;mt<4;mt++){
        int g = wv*4+mt;
        #pragma unroll
        for (int r=0;r<4;r++){
          int pix = (yt*8 + (g>>1))*32 + (g&1)*16 + q*4 + r;
          size_t o = aidx(b, icv, pix) + e;
          float v = acc[mt][nt][r] + b2f(g_xp[o]);
          g_tb[o] = f2b(v);
          s0 += v; s1 += v*v;
        }
      }
    }
    s0 += __shfl_down(s0,32); s1 += __shfl_down(s1,32);
    s0 += __shfl_down(s0,16); s1 += __shfl_down(s1,16);
    if (lane < 16 && ok){
      atomicAdd(&g_gn2sum[(b*24+oc)*2],   s0);
      atomicAdd(&g_gn2sum[(b*24+oc)*2+1], s1);
    }
  }
}

// ====== fuse_k: merged fuse_a+fuse_b. 128 blocks x 1024 thr (1 pixel/thread) ======
// gn2 affine from g_gn2sum; block-local GN3 stats; writes F,G; gram row -> g_gramp
// (round-10 per-(b,seg) format: seg0 holds full sum, segs 1..3 zero)
__launch_bounds__(1024, 1)
__global__ void fuse_k(int s, int nv){
  __shared__ float sS3[16], sGrow[5], sAff[96];
  const int b = blockIdx.x, t = threadIdx.x;
  const int lane = t & 63;
  if (t < 16) sS3[t] = 0.f;
  else if (t < 21) sGrow[t-16] = 0.f;
  if (t < 24){
    int g = t/3;
    float S = g_gn2sum[(b*24+g*3)*2]   + g_gn2sum[(b*24+g*3+1)*2]   + g_gn2sum[(b*24+g*3+2)*2];
    float Q = g_gn2sum[(b*24+g*3)*2+1] + g_gn2sum[(b*24+g*3+1)*2+1] + g_gn2sum[(b*24+g*3+2)*2+1];
    float m = S*(1.f/3072.f);
    float rs = rsqrtf(fmaxf(Q*(1.f/3072.f) - m*m, 0.f) + 1e-5f);
    float sc = rs*g_params[P_G2G+t];
    sAff[t] = sc; sAff[24+t] = g_params[P_G2B+t] - m*sc;
  }
  __syncthreads();
  float tv[24], xv[24];
  ld24c(g_tb, b, t, tv);
  ld24c(g_X + (size_t)s*cBD, b, t, xv);
  float p0[8], p1[8];
  #pragma unroll
  for (int g=0;g<8;g++){ p0[g]=0.f; p1[g]=0.f; }
  #pragma unroll
  for (int c=0;c<24;c++){
    int g = c/3;
    float v = fmaxf(xv[c] + tv[c]*sAff[c] + sAff[24+c], 0.f);
    p0[g] += v; p1[g] += v*v;
  }
  #pragma unroll
  for (int g=0;g<8;g++){
    for (int off=32;off>0;off>>=1){ p0[g]+=__shfl_down(p0[g],off,64); p1[g]+=__shfl_down(p1[g],off,64); }
  }
  if (lane==0){
    #pragma unroll
    for (int g=0;g<8;g++){ atomicAdd(&sS3[g*2], p0[g]); atomicAdd(&sS3[g*2+1], p1[g]); }
  }
  __syncthreads();
  if (t < 24){
    int g = t/3;
    float m3 = sS3[g*2]*(1.f/3072.f);
    float rs3 = rsqrtf(fmaxf(sS3[g*2+1]*(1.f/3072.f) - m3*m3, 0.f) + 1e-5f);
    float sc3 = rs3*g_params[P_G3G+t];
    sAff[48+t] = sc3; sAff[72+t] = g_params[P_G3B+t] - m3*sc3;
  }
  __syncthreads();
  float fv[24], gl[24];
  #pragma unroll
  for (int c=0;c<24;c++){
    float v = fmaxf(xv[c] + tv[c]*sAff[c] + sAff[24+c], 0.f);
    fv[c] = v*sAff[48+c] + sAff[72+c];
    gl[c] = b2f(f2b(fv[c] - xv[c]));   // bf16-rounded, matches stored G
  }
  st24c(g_F + (size_t)s*cBD, b, t, fv);
  st24c(g_G + (size_t)s*cBD, b, t, gl);
  if (nv > 0){
    float part[5];
    #pragma unroll
    for (int j=0;j<5;j++) part[j]=0.f;
    #pragma unroll
    for (int j=0;j<5;j++){
      if (j>=nv) continue;
      float acc=0.f;
      if (j==s){
        #pragma unroll
        for (int c=0;c<24;c++) acc += gl[c]*gl[c];
      } else {
        float gv[24];
        ld24c(g_G + (size_t)j*cBD, b, t, gv);
        #pragma unroll
        for (int c=0;c<24;c++) acc += gl[c]*gv[c];
      }
      part[j]=acc;
    }
    #pragma unroll
    for (int j=0;j<5;j++){
      float v = part[j];
      for (int off=32;off>0;off>>=1) v += __shfl_down(v,off,64);
      if (lane==0 && j<nv) atomicAdd(&sGrow[j], v);
    }
  }
  __syncthreads();
  if (nv > 0 && t < 20){
    int seg = t/5, j = t%5;
    g_gramp[((b*4+seg)*5 + s)*5 + j] = (seg==0 && j<nv) ? sGrow[j] : 0.f;
  }
}

// ---- merged solve+xnew: per-block local gram refresh + Cholesky (thread 0), then axpy ----
template<int N>
__device__ __forceinline__ void chol_alpha(const float Kf[5][5], float* alpha){
  double K[N][N];
  #pragma unroll
  for (int i=0;i<N;i++)
    #pragma unroll
    for (int j=0;j<N;j++)
      K[i][j] = (double)Kf[i][j] + (i==j ? 1e-4 : 0.0);
  #pragma unroll
  for (int c=0;c<N;c++){
    double d = K[c][c];
    #pragma unroll
    for (int k2=0;k2<c;k2++) d -= K[c][k2]*K[c][k2];
    d = sqrt(fmax(d, 1e-300));
    K[c][c] = d;
    double inv = 1.0/d;
    #pragma unroll
    for (int r=c+1;r<N;r++){
      double v = K[r][c];
      #pragma unroll
      for (int k2=0;k2<c;k2++) v -= K[r][k2]*K[c][k2];
      K[r][c] = v*inv;
    }
  }
  double y[N];
  #pragma unroll
  for (int i=0;i<N;i++){
    double v = 1.0;
    #pragma unroll
    for (int j=0;j<i;j++) v -= K[i][j]*y[j];
    y[i] = v / K[i][i];
  }
  double w[N];
  #pragma unroll
  for (int i=N-1;i>=0;i--){
    double v = y[i];
    #pragma unroll
    for (int j=i+1;j<N;j++) v -= K[j][i]*w[j];
    w[i] = v / K[i][i];
  }
  double sum = 0.0;
  #pragma unroll
  for (int i=0;i<N;i++) sum += w[i];
  double invs = 1.0/sum;
  #pragma unroll
  for (int i=0;i<N;i++) alpha[i] = (float)(w[i]*invs);
}

// grid 512 (b*4+ch), 256 thr
__global__ void xns_k(int s, int n, int rA, int nvA, int rB, int nvB){
  __shared__ float sAlpha[5];
  if (blockIdx.x < 8) g_gn1sum[blockIdx.x*256 + threadIdx.x] = 0.f;
  const int b = blockIdx.x >> 2, ch = blockIdx.x & 3;
  const int t = threadIdx.x;
  if (t == 0){
    float Kf[5][5];
    for (int i=0;i<n;i++)
      for (int j=0;j<n;j++) Kf[i][j] = g_gram[b*25 + i*5 + j];
    for (int j=0;j<nvA;j++){
      float v = g_gramp[((b*4+0)*5 + rA)*5 + j] + g_gramp[((b*4+1)*5 + rA)*5 + j]
              + g_gramp[((b*4+2)*5 + rA)*5 + j] + g_gramp[((b*4+3)*5 + rA)*5 + j];
      Kf[rA][j] = v; Kf[j][rA] = v;
    }
    if (rB >= 0){
      for (int j=0;j<nvB;j++){
        float v = g_gramp[((b*4+0)*5 + rB)*5 + j] + g_gramp[((b*4+1)*5 + rB)*5 + j]
                + g_gramp[((b*4+2)*5 + rB)*5 + j] + g_gramp[((b*4+3)*5 + rB)*5 + j];
        Kf[rB][j] = v; Kf[j][rB] = v;
      }
    }
    if (ch == 0){
      for (int j=0;j<nvA;j++){ g_gram[b*25+rA*5+j]=Kf[rA][j]; g_gram[b*25+j*5+rA]=Kf[rA][j]; }
      if (rB >= 0)
        for (int j=0;j<nvB;j++){ g_gram[b*25+rB*5+j]=Kf[rB][j]; g_gram[b*25+j*5+rB]=Kf[rB][j]; }
    }
    float al[5];
    if (n==2) chol_alpha<2>(Kf, al);
    else if (n==3) chol_alpha<3>(Kf, al);
    else if (n==4) chol_alpha<4>(Kf, al);
    else chol_alpha<5>(Kf, al);
    for (int j=0;j<n;j++) sAlpha[j] = al[j];
  }
  __syncthreads();
  float a[5];
  for (int j=0;j<n;j++) a[j] = sAlpha[j];
  const size_t base = (size_t)b*DD + (size_t)ch*6144;
  #pragma unroll
  for (int i=0;i<3;i++){
    size_t off = base + (size_t)i*2048 + (size_t)t*8;
    float acc[8];
    #pragma unroll
    for (int e=0;e<8;e++) acc[e]=0.f;
    for (int j=0;j<n;j++){
      short8 f = *(const short8*)&g_F[(size_t)j*cBD + off];
      float aj = a[j];
      #pragma unroll
      for (int e=0;e<8;e++) acc[e] += aj*b2f((ushortT)f[e]);
    }
    short8 o;
    #pragma unroll
    for (int e=0;e<8;e++) o[e] = (short)f2b(acc[e]);
    *(short8*)&g_X[(size_t)s*cBD + off] = o;
  }
}

// ---- post: bn(relu(F[4])) + 8x8 avgpool ----
__global__ void post_pool_k(){
  int i = blockIdx.x*256+threadIdx.x; if (i >= BB*CHAN*16) return;
  const ushortT* z = g_F + 4*cBD;
  int pw = i&3, ph=(i>>2)&3, c=(i>>4)%CHAN, bi=i/(CHAN*16);
  int icv = c>>3, e = c&7;
  float inv = 1.f/(BB*HW);
  float mean = g_stats2b[c*2]*inv;
  float var = fmaxf(g_stats2b[c*2+1]*inv - mean*mean, 0.f);
  float rstd = rsqrtf(var + 1e-5f);
  float gg=g_params[P_POG+c], bv=g_params[P_POB+c];
  float s=0.f;
  for (int dy=0;dy<8;dy++)
    for (int dx=0;dx<8;dx++){
      int pix = (ph*8+dy)*32 + pw*8+dx;
      float v = fmaxf(b2f(z[aidx(bi,icv,pix) + e]), 0.f);
      s += (v-mean)*rstd*gg + bv;
    }
  g_pooled[i] = s*(1.f/64.f);
}

__global__ void fc_k(void* __restrict__ out){
  int i = blockIdx.x*256+threadIdx.x; if (i>=BB*10) return;
  int j=i%10, bi=i/10;
  float s = g_params[P_FCB+j];
  for (int k=0;k<384;k++) s += g_pooled[bi*384+k]*g_params[P_FCW+j*384+k];
  if (g_isbf16) ((bf16*)out)[i] = __float2bfloat16(s);
  else ((float*)out)[i] = s;
}

extern "C" void kernel_launch(void* const* d_in, const int* in_sizes, int n_in,
                              void* d_out, int out_size, void* d_ws, size_t ws_size,
                              hipStream_t stream){
  const void* x   = d_in[0];
  const void* pcw = d_in[1];
  const void* pcb = d_in[2];
  const void* pbg = d_in[3];
  const void* pbb = d_in[4];
  const void* w1  = d_in[5];
  const void* g1g = d_in[6];
  const void* g1b = d_in[7];
  const void* w2  = d_in[8];
  const void* g2g = d_in[9];
  const void* g2b = d_in[10];
  const void* g3g = d_in[11];
  const void* g3b = d_in[12];
  const void* pog = d_in[13];
  const void* pob = d_in[14];
  const void* fcw = d_in[15];
  const void* fcb = d_in[16];
  (void)d_ws; (void)ws_size;

  const int gPix = (int)(BB*HW/256); // 512

  auto feval = [&](int s, int nv){
    conv1_k<<<512,256,0,stream>>>(s);
    conv2_k<<<512,256,0,stream>>>();
    fuse_k<<<128,1024,0,stream>>>(s, nv);
  };

  detect_k<<<1,64,0,stream>>>(g1g);
  cvt_params_k<<<1,256,0,stream>>>(pcw,pcb,pbg,pbb,g1g,g1b,g2g,g2b,g3g,g3b,pog,pob,fcw,fcb);
  wtm_k<<<126,256,0,stream>>>(w1, w2);

  // pre stage
  preconv_k<<<gPix,256,0,stream>>>(x);
  bnstat2_k<false><<<512,192,0,stream>>>(0);
  bn_apply_k<<<gPix,256,0,stream>>>();

  // anderson init
  zeroX0_k<<<1536,256,0,stream>>>();
  feval(0, 1);
  copyF0toX1_k<<<1536,256,0,stream>>>();
  feval(1, 2);

  // anderson loop
  for (int k=2;k<25;k++){
    int n = k<5 ? k : 5;
    int s = k%5;
    int nv = (k+1<5)?(k+1):5;
    if (k==2) xns_k<<<512,256,0,stream>>>(s, 2, 0, 1, 1, 2);
    else      xns_k<<<512,256,0,stream>>>(s, n, (k-1)%5, n, -1, 0);
    feval(s, (k<24) ? nv : 0);
  }

  // z_star = X[4]; final z = resnet_f(z_star) == F[4] (computed at k=24)
  bnstat2_k<true><<<512,192,0,stream>>>(1);
  post_pool_k<<<(BB*CHAN*16+255)/256,256,0,stream>>>();
  fc_k<<<(BB*10+255)/256,256,0,stream>>>(d_out);
}